// Round 1
// baseline (1188.109 us; speedup 1.0000x reference)
//
#include <hip/hip_runtime.h>

typedef unsigned short ushort;
typedef float f32x4 __attribute__((ext_vector_type(4)));
typedef __bf16 bf16x8 __attribute__((ext_vector_type(8)));
typedef ushort u16x4 __attribute__((ext_vector_type(4)));
typedef ushort u16x8 __attribute__((ext_vector_type(8)));

#define LOG2E 1.4426950408889634f

__device__ __forceinline__ ushort f2bu(float f) { __bf16 b = (__bf16)f; return __builtin_bit_cast(ushort, b); }
__device__ __forceinline__ float  bu2f(ushort u) { return (float)__builtin_bit_cast(__bf16, u); }

__device__ __forceinline__ void gld16(const void* g, void* l) {
    __builtin_amdgcn_global_load_lds((const __attribute__((address_space(1))) unsigned int*)g,
                                     (__attribute__((address_space(3))) unsigned int*)l, 16, 0, 0);
}

// ---------------- convert x fp32 -> bf16 ----------------
__global__ __launch_bounds__(256) void k_cvt(const float* __restrict__ in, ushort* __restrict__ out, int n4) {
    int i = blockIdx.x * 256 + threadIdx.x;
    if (i < n4) {
        float4 v = ((const float4*)in)[i];
        u16x4 o = { f2bu(v.x), f2bu(v.y), f2bu(v.z), f2bu(v.w) };
        ((u16x4*)out)[i] = o;
    }
}

// ---------------- transpose weight fp32 [k][n] -> bf16 [n][k] ----------------
__global__ __launch_bounds__(256) void k_twt(const float* __restrict__ W, ushort* __restrict__ Wt) {
    __shared__ float t[32][33];
    int n0 = blockIdx.x * 32, k0 = blockIdx.y * 32;
    int tx = threadIdx.x & 31, ty = threadIdx.x >> 5;
#pragma unroll
    for (int i = 0; i < 32; i += 8) t[ty + i][tx] = W[(size_t)(k0 + ty + i) * 2048 + n0 + tx];
    __syncthreads();
#pragma unroll
    for (int i = 0; i < 32; i += 8) Wt[(size_t)(n0 + ty + i) * 2048 + k0 + tx] = f2bu(t[tx][ty + i]);
}

// ---------------- rope cos/sin table [4096][32][2] ----------------
__global__ __launch_bounds__(256) void k_rope(float* __restrict__ tab) {
    int idx = blockIdx.x * 256 + threadIdx.x;   // 131072 total
    int t = idx >> 5, j = idx & 31;
    float fr = exp2f(-10.0f * (float)j / 31.0f);      // (1/1024)^(j/31)
    float th = (float)t * fr;
    tab[idx * 2]     = cosf(th);
    tab[idx * 2 + 1] = sinf(th);
}

// ---------------- bf16 GEMM: C[M=16384][2048] = A[M][2048] * Bt[n][k]^T ----------------
template <int OUTF32>
__global__ __launch_bounds__(256) void k_gemm(const ushort* __restrict__ A, const ushort* __restrict__ Bt,
                                              float* __restrict__ Cf, ushort* __restrict__ Cb) {
    __shared__ __align__(16) ushort la[2][128][32];
    __shared__ __align__(16) ushort lb[2][128][32];
    const int tid = threadIdx.x;
    const int wid = tid >> 6, lane = tid & 63;
    const int wr = wid >> 1, wc = wid & 1;
    const int lrow = lane & 15, lko = (lane >> 4) * 8;
    const size_t m0 = (size_t)blockIdx.x * 128, n0 = (size_t)blockIdx.y * 128;
    const char* Ab = (const char*)A;
    const char* Bb = (const char*)Bt;

    f32x4 acc[4][4] = {};

    auto stage = [&](int buf, int kk) {
#pragma unroll
        for (int i = 0; i < 2; ++i) {
            int db = i * 4096 + tid * 16;
            int row = db >> 6, cb = db & 63;
            gld16(Ab + ((m0 + row) * 2048 + kk) * 2 + cb, (char*)(&la[buf][0][0]) + db);
            gld16(Bb + ((n0 + row) * 2048 + kk) * 2 + cb, (char*)(&lb[buf][0][0]) + db);
        }
    };

    stage(0, 0);
    int cur = 0;
    for (int kk = 32; kk <= 2048; kk += 32) {
        __syncthreads();
        if (kk < 2048) stage(cur ^ 1, kk);
        bf16x8 af[4], bfr[4];
#pragma unroll
        for (int mi = 0; mi < 4; ++mi) af[mi] = *(const bf16x8*)&la[cur][wr * 64 + mi * 16 + lrow][lko];
#pragma unroll
        for (int ni = 0; ni < 4; ++ni) bfr[ni] = *(const bf16x8*)&lb[cur][wc * 64 + ni * 16 + lrow][lko];
#pragma unroll
        for (int mi = 0; mi < 4; ++mi)
#pragma unroll
            for (int ni = 0; ni < 4; ++ni)
                acc[mi][ni] = __builtin_amdgcn_mfma_f32_16x16x32_bf16(af[mi], bfr[ni], acc[mi][ni], 0, 0, 0);
        cur ^= 1;
    }
#pragma unroll
    for (int mi = 0; mi < 4; ++mi)
#pragma unroll
        for (int ni = 0; ni < 4; ++ni)
#pragma unroll
            for (int i = 0; i < 4; ++i) {
                size_t row = m0 + wr * 64 + mi * 16 + (lane >> 4) * 4 + i;
                size_t col = n0 + wc * 64 + ni * 16 + lrow;
                if (OUTF32) Cf[row * 2048 + col] = acc[mi][ni][i];
                else        Cb[row * 2048 + col] = f2bu(acc[mi][ni][i]);
            }
}

// ---------------- rope + reshape ----------------
// mode 0: q -> natural [bh][t][d] (roped)
// mode 1: k -> natural [bh][t][d] (roped) + kT [bh][d][t] (roped, * k_decay[s])
// mode 2: v -> vT [bh][e][t]
__global__ __launch_bounds__(256) void k_reshape(const ushort* __restrict__ Cin, ushort* __restrict__ outN,
                                                 ushort* __restrict__ outT, const float* __restrict__ rt, int mode) {
    int blk = blockIdx.x;           // (bh)*32 + c
    int c = blk & 31, bh = blk >> 5, b = bh >> 4, h = bh & 15;
    __shared__ __align__(16) ushort lt[128][136];
    int tid = threadIdx.x;
    int d = tid & 63, rq = tid >> 6;
    float slope = exp2f(-0.5f * (float)(h + 1));
    float l2r = -slope * LOG2E;
    for (int rp = 0; rp < 32; ++rp) {
        int tr = rp * 4 + rq;
        int t = c * 128 + tr;
        const ushort* src = Cin + ((size_t)(b * 4096 + t)) * 2048 + h * 128;
        float x1 = bu2f(src[d]), x2 = bu2f(src[d + 64]);
        float y1 = x1, y2 = x2;
        if (mode != 2 && d < 32) {
            float cs = rt[(t * 32 + d) * 2], sn = rt[(t * 32 + d) * 2 + 1];
            y1 = x1 * cs + x2 * sn;
            y2 = x2 * cs - x1 * sn;
        }
        if (mode != 2) {
            ushort* dstN = outN + ((size_t)bh * 4096 + t) * 128;
            dstN[d] = f2bu(y1); dstN[d + 64] = f2bu(y2);
        }
        if (mode != 0) { lt[tr][d] = f2bu(y1); lt[tr][d + 64] = f2bu(y2); }
    }
    if (mode == 0) return;
    __syncthreads();
    int dd = tid >> 1, half = tid & 1;
    ushort* dstT = outT + ((size_t)bh * 128 + dd) * 4096 + c * 128 + half * 64;
    for (int j8 = 0; j8 < 8; ++j8) {
        u16x8 tmp;
#pragma unroll
        for (int j = 0; j < 8; ++j) {
            int s = half * 64 + j8 * 8 + j;
            float v = bu2f(lt[s][dd]);
            if (mode == 1) v *= exp2f(l2r * (float)(127 - s));
            tmp[j] = f2bu(v);
        }
        *(u16x8*)(dstT + j8 * 8) = tmp;
    }
}

// ---------------- pass1: chunk-local KVt[e][d] = sum_s v[s][e]*kd[s]*k[s][d] ----------------
__global__ __launch_bounds__(256) void k_pass1(const ushort* __restrict__ kTa, const ushort* __restrict__ vTa,
                                               float* __restrict__ KVc) {
    int blk = blockIdx.x;           // bh*32 + c
    int c = blk & 31, bh = blk >> 5;
    __shared__ __align__(16) ushort lv[128][136];
    __shared__ __align__(16) ushort lk[128][136];
    int tid = threadIdx.x;
#pragma unroll
    for (int i = 0; i < 8; ++i) {
        int idx = i * 256 + tid; int row = idx >> 4, cb = (idx & 15) * 8;
        *(bf16x8*)&lv[row][cb] = *(const bf16x8*)(vTa + ((size_t)bh * 128 + row) * 4096 + c * 128 + cb);
        *(bf16x8*)&lk[row][cb] = *(const bf16x8*)(kTa + ((size_t)bh * 128 + row) * 4096 + c * 128 + cb);
    }
    __syncthreads();
    int wid = tid >> 6, lane = tid & 63, wr = wid >> 1, wc = wid & 1;
    int lrow = lane & 15, lko = (lane >> 4) * 8;
    f32x4 acc[4][4] = {};
#pragma unroll
    for (int ks = 0; ks < 4; ++ks) {
        bf16x8 a[4], bb[4];
#pragma unroll
        for (int mi = 0; mi < 4; ++mi) a[mi] = *(const bf16x8*)&lv[wr * 64 + mi * 16 + lrow][ks * 32 + lko];
#pragma unroll
        for (int ni = 0; ni < 4; ++ni) bb[ni] = *(const bf16x8*)&lk[wc * 64 + ni * 16 + lrow][ks * 32 + lko];
#pragma unroll
        for (int mi = 0; mi < 4; ++mi)
#pragma unroll
            for (int ni = 0; ni < 4; ++ni)
                acc[mi][ni] = __builtin_amdgcn_mfma_f32_16x16x32_bf16(a[mi], bb[ni], acc[mi][ni], 0, 0, 0);
    }
    float* out = KVc + (size_t)blk * 16384;
#pragma unroll
    for (int mi = 0; mi < 4; ++mi)
#pragma unroll
        for (int ni = 0; ni < 4; ++ni)
#pragma unroll
            for (int i = 0; i < 4; ++i)
                out[(wr * 64 + mi * 16 + (lane >> 4) * 4 + i) * 128 + wc * 64 + ni * 16 + lrow] = acc[mi][ni][i];
}

// ---------------- pass2: prefix scan over chunks (fp32 state), emit bf16 prefixes ----------------
__global__ __launch_bounds__(256) void k_scan(const float* __restrict__ KVc, ushort* __restrict__ KVbf) {
    int bh = blockIdx.x >> 4, seg = blockIdx.x & 15, h = bh & 15;
    float slope = exp2f(-0.5f * (float)(h + 1));
    float rC = exp2f(-slope * LOG2E * 128.0f);
    int off = seg * 1024 + threadIdx.x * 4;
    f32x4 st = {0.f, 0.f, 0.f, 0.f};
    for (int c = 0; c < 32; ++c) {
        size_t base = ((size_t)bh * 32 + c) * 16384 + off;
        f32x4 v = *(const f32x4*)(KVc + base);
        u16x4 o = { f2bu(st.x), f2bu(st.y), f2bu(st.z), f2bu(st.w) };
        *(u16x4*)(KVbf + base) = o;
        st = st * rC + v;
    }
}

// ---------------- pass3: out = diag(q_decay)*(q@KV) + (dmask o (q@k^T))@v ----------------
__global__ __launch_bounds__(512) void k_pass3(const ushort* __restrict__ qa, const ushort* __restrict__ ka,
                                               const ushort* __restrict__ vTa, const ushort* __restrict__ KVbf,
                                               ushort* __restrict__ attn) {
    int blk = blockIdx.x;           // bh*32 + c
    int c = blk & 31, bh = blk >> 5, h = bh & 15;
    __shared__ __align__(16) ushort lq[128][136];
    __shared__ __align__(16) ushort lk[128][136];   // later reused as P
    __shared__ __align__(16) ushort lv[128][136];
    int tid = threadIdx.x;
#pragma unroll
    for (int i = 0; i < 4; ++i) {
        int idx = i * 512 + tid; int row = idx >> 4, cb = (idx & 15) * 8;
        *(bf16x8*)&lq[row][cb] = *(const bf16x8*)(qa + ((size_t)bh * 4096 + c * 128 + row) * 128 + cb);
        *(bf16x8*)&lk[row][cb] = *(const bf16x8*)(ka + ((size_t)bh * 4096 + c * 128 + row) * 128 + cb);
        *(bf16x8*)&lv[row][cb] = *(const bf16x8*)(vTa + ((size_t)bh * 128 + row) * 4096 + c * 128 + cb);
    }
    __syncthreads();
    int wid = tid >> 6, lane = tid & 63;
    int wr = wid >> 2, wc = wid & 3;          // 2 x 4 wave grid: 64 t-rows x 32 cols
    int lrow = lane & 15, lko = (lane >> 4) * 8;
    float slope = exp2f(-0.5f * (float)(h + 1));
    float l2r = -slope * LOG2E;

    // scores = q @ k^T (quadrant t: wr*64.., s: wc*32..)
    f32x4 accs[4][2] = {};
#pragma unroll
    for (int kd = 0; kd < 4; ++kd) {
        bf16x8 a[4], bb[2];
#pragma unroll
        for (int mi = 0; mi < 4; ++mi) a[mi] = *(const bf16x8*)&lq[wr * 64 + mi * 16 + lrow][kd * 32 + lko];
#pragma unroll
        for (int ni = 0; ni < 2; ++ni) bb[ni] = *(const bf16x8*)&lk[wc * 32 + ni * 16 + lrow][kd * 32 + lko];
#pragma unroll
        for (int mi = 0; mi < 4; ++mi)
#pragma unroll
            for (int ni = 0; ni < 2; ++ni)
                accs[mi][ni] = __builtin_amdgcn_mfma_f32_16x16x32_bf16(a[mi], bb[ni], accs[mi][ni], 0, 0, 0);
    }
    __syncthreads();   // everyone done reading lk; it becomes the P buffer

    // inter = q @ KV (B-frags straight from global bf16 KV prefix)
    f32x4 acc[4][2] = {};
#pragma unroll
    for (int kd = 0; kd < 4; ++kd) {
        bf16x8 a[4], bb[2];
#pragma unroll
        for (int mi = 0; mi < 4; ++mi) a[mi] = *(const bf16x8*)&lq[wr * 64 + mi * 16 + lrow][kd * 32 + lko];
#pragma unroll
        for (int ni = 0; ni < 2; ++ni)
            bb[ni] = *(const bf16x8*)(KVbf + (size_t)blk * 16384 + (size_t)(wc * 32 + ni * 16 + lrow) * 128 + kd * 32 + lko);
#pragma unroll
        for (int mi = 0; mi < 4; ++mi)
#pragma unroll
            for (int ni = 0; ni < 2; ++ni)
                acc[mi][ni] = __builtin_amdgcn_mfma_f32_16x16x32_bf16(a[mi], bb[ni], acc[mi][ni], 0, 0, 0);
    }

    // P = dmask o scores  -> write bf16 into lk
#pragma unroll
    for (int mi = 0; mi < 4; ++mi)
#pragma unroll
        for (int ni = 0; ni < 2; ++ni)
#pragma unroll
            for (int i = 0; i < 4; ++i) {
                int t = wr * 64 + mi * 16 + (lane >> 4) * 4 + i;
                int s = wc * 32 + ni * 16 + lrow;
                int dt = t - s;
                float w = (dt < 0) ? 0.f : exp2f(l2r * (float)dt);
                lk[t][s] = f2bu(accs[mi][ni][i] * w);
            }

    // scale inter by q_decay[t] = r^(t+1)
#pragma unroll
    for (int mi = 0; mi < 4; ++mi)
#pragma unroll
        for (int ni = 0; ni < 2; ++ni)
#pragma unroll
            for (int i = 0; i < 4; ++i) {
                int t = wr * 64 + mi * 16 + (lane >> 4) * 4 + i;
                acc[mi][ni][i] *= exp2f(l2r * (float)(t + 1));
            }
    __syncthreads();

    // intra: P @ v (A = P from lk, B from vT)
#pragma unroll
    for (int ks = 0; ks < 4; ++ks) {
        bf16x8 a[4], bb[2];
#pragma unroll
        for (int mi = 0; mi < 4; ++mi) a[mi] = *(const bf16x8*)&lk[wr * 64 + mi * 16 + lrow][ks * 32 + lko];
#pragma unroll
        for (int ni = 0; ni < 2; ++ni) bb[ni] = *(const bf16x8*)&lv[wc * 32 + ni * 16 + lrow][ks * 32 + lko];
#pragma unroll
        for (int mi = 0; mi < 4; ++mi)
#pragma unroll
            for (int ni = 0; ni < 2; ++ni)
                acc[mi][ni] = __builtin_amdgcn_mfma_f32_16x16x32_bf16(a[mi], bb[ni], acc[mi][ni], 0, 0, 0);
    }

    ushort* out = attn + ((size_t)bh * 4096 + c * 128) * 128;
#pragma unroll
    for (int mi = 0; mi < 4; ++mi)
#pragma unroll
        for (int ni = 0; ni < 2; ++ni)
#pragma unroll
            for (int i = 0; i < 4; ++i)
                out[(size_t)(wr * 64 + mi * 16 + (lane >> 4) * 4 + i) * 128 + wc * 32 + ni * 16 + lrow] =
                    f2bu(acc[mi][ni][i]);
}

// ---------------- RMS norm + [b,h,t,d] -> [token][e] ----------------
__global__ __launch_bounds__(256) void k_rms(const ushort* __restrict__ attn, const float* __restrict__ w,
                                             ushort* __restrict__ normed) {
    int tok = blockIdx.x; int b = tok >> 12, t = tok & 4095;
    int tid = threadIdx.x;
    int e0 = tid * 8; int h = e0 >> 7, d0 = e0 & 127;
    bf16x8 v = *(const bf16x8*)(attn + (((size_t)(b * 16 + h) * 4096 + t) * 128 + d0));
    float f[8]; float ss = 0.f;
#pragma unroll
    for (int j = 0; j < 8; ++j) { f[j] = (float)v[j]; ss += f[j] * f[j]; }
#pragma unroll
    for (int o = 1; o < 64; o <<= 1) ss += __shfl_xor(ss, o, 64);
    __shared__ float red[4];
    if ((tid & 63) == 0) red[tid >> 6] = ss;
    __syncthreads();
    float tot = red[0] + red[1] + red[2] + red[3];
    float sc = rsqrtf(tot * (1.0f / 2048.0f) + 1e-5f);
    u16x8 ov;
#pragma unroll
    for (int j = 0; j < 8; ++j) ov[j] = f2bu(f[j] * sc * w[e0 + j]);
    *(u16x8*)(normed + (size_t)tok * 2048 + e0) = ov;
}

// ---------------- launch ----------------
// ws layout (MiB): 0 WtQ, 8 WtK, 16 WtV, 24 WtO, 32 xb(64), 96 Cbuf(64),
// 160 qa(64), 224 ka(64), 288 kTa(64), 352 vTa(64), 416 ropetab(1).
// Reuse after liveness ends: KVc f32 @32 (128), KVbf @288 (64), attn @32 (64), normed @96 (64).
// Requires ws_size >= 417 MiB.
extern "C" void kernel_launch(void* const* d_in, const int* in_sizes, int n_in,
                              void* d_out, int out_size, void* d_ws, size_t ws_size,
                              hipStream_t stream) {
    const float* x    = (const float*)d_in[0];
    const float* Wq   = (const float*)d_in[1];
    const float* Wk   = (const float*)d_in[2];
    const float* Wv   = (const float*)d_in[3];
    const float* Wo   = (const float*)d_in[4];
    const float* rmsw = (const float*)d_in[5];
    char* ws = (char*)d_ws;
    const size_t MiB = 1ull << 20;
    ushort* WtQ  = (ushort*)(ws + 0);
    ushort* WtK  = (ushort*)(ws + 8 * MiB);
    ushort* WtV  = (ushort*)(ws + 16 * MiB);
    ushort* WtO  = (ushort*)(ws + 24 * MiB);
    ushort* xb   = (ushort*)(ws + 32 * MiB);
    ushort* Cbuf = (ushort*)(ws + 96 * MiB);
    ushort* qa   = (ushort*)(ws + 160 * MiB);
    ushort* ka   = (ushort*)(ws + 224 * MiB);
    ushort* kTa  = (ushort*)(ws + 288 * MiB);
    ushort* vTa  = (ushort*)(ws + 352 * MiB);
    float*  rt   = (float*)(ws + 416 * MiB);
    float*  KVc  = (float*)(ws + 32 * MiB);
    ushort* KVbf = (ushort*)(ws + 288 * MiB);
    ushort* attn = (ushort*)(ws + 32 * MiB);
    ushort* nrm  = (ushort*)(ws + 96 * MiB);

    k_cvt<<<32768, 256, 0, stream>>>(x, xb, 8388608);
    dim3 gw(64, 64);
    k_twt<<<gw, 256, 0, stream>>>(Wq, WtQ);
    k_twt<<<gw, 256, 0, stream>>>(Wk, WtK);
    k_twt<<<gw, 256, 0, stream>>>(Wv, WtV);
    k_twt<<<gw, 256, 0, stream>>>(Wo, WtO);
    k_rope<<<512, 256, 0, stream>>>(rt);

    dim3 gg(128, 16);
    k_gemm<0><<<gg, 256, 0, stream>>>(xb, WtQ, nullptr, Cbuf);
    k_reshape<<<2048, 256, 0, stream>>>(Cbuf, qa, nullptr, rt, 0);
    k_gemm<0><<<gg, 256, 0, stream>>>(xb, WtK, nullptr, Cbuf);
    k_reshape<<<2048, 256, 0, stream>>>(Cbuf, ka, kTa, rt, 1);
    k_gemm<0><<<gg, 256, 0, stream>>>(xb, WtV, nullptr, Cbuf);
    k_reshape<<<2048, 256, 0, stream>>>(Cbuf, nullptr, vTa, rt, 2);

    k_pass1<<<2048, 256, 0, stream>>>(kTa, vTa, KVc);
    k_scan<<<1024, 256, 0, stream>>>(KVc, KVbf);
    k_pass3<<<2048, 512, 0, stream>>>(qa, ka, vTa, KVbf, attn);

    k_rms<<<16384, 256, 0, stream>>>(attn, rmsw, nrm);
    k_gemm<1><<<gg, 256, 0, stream>>>(nrm, WtO, (float*)d_out, nullptr);
}

// Round 2
// 898.038 us; speedup vs baseline: 1.3230x; 1.3230x over previous
//
#include <hip/hip_runtime.h>

typedef unsigned short ushort;
typedef float f32x4 __attribute__((ext_vector_type(4)));
typedef __bf16 bf16x8 __attribute__((ext_vector_type(8)));
typedef ushort u16x4 __attribute__((ext_vector_type(4)));
typedef ushort u16x8 __attribute__((ext_vector_type(8)));

#define LOG2E 1.4426950408889634f

__device__ __forceinline__ ushort f2bu(float f) { __bf16 b = (__bf16)f; return __builtin_bit_cast(ushort, b); }
__device__ __forceinline__ float  bu2f(ushort u) { return (float)__builtin_bit_cast(__bf16, u); }

__device__ __forceinline__ void gld16(const void* g, void* l) {
    __builtin_amdgcn_global_load_lds((const __attribute__((address_space(1))) unsigned int*)g,
                                     (__attribute__((address_space(3))) unsigned int*)l, 16, 0, 0);
}

// ---------------- convert x fp32 -> bf16 ----------------
__global__ __launch_bounds__(256) void k_cvt(const float* __restrict__ in, ushort* __restrict__ out, int n4) {
    int i = blockIdx.x * 256 + threadIdx.x;
    if (i < n4) {
        float4 v = ((const float4*)in)[i];
        u16x4 o = { f2bu(v.x), f2bu(v.y), f2bu(v.z), f2bu(v.w) };
        ((u16x4*)out)[i] = o;
    }
}

// ---------------- transpose weight fp32 [k][n] -> bf16 [n][k] ----------------
__global__ __launch_bounds__(256) void k_twt(const float* __restrict__ W, ushort* __restrict__ Wt) {
    __shared__ float t[32][33];
    int n0 = blockIdx.x * 32, k0 = blockIdx.y * 32;
    int tx = threadIdx.x & 31, ty = threadIdx.x >> 5;
#pragma unroll
    for (int i = 0; i < 32; i += 8) t[ty + i][tx] = W[(size_t)(k0 + ty + i) * 2048 + n0 + tx];
    __syncthreads();
#pragma unroll
    for (int i = 0; i < 32; i += 8) Wt[(size_t)(n0 + ty + i) * 2048 + k0 + tx] = f2bu(t[tx][ty + i]);
}

// ---------------- rope cos/sin table [4096][32][2] ----------------
__global__ __launch_bounds__(256) void k_rope(float* __restrict__ tab) {
    int idx = blockIdx.x * 256 + threadIdx.x;   // 131072 total
    int t = idx >> 5, j = idx & 31;
    float fr = exp2f(-10.0f * (float)j / 31.0f);      // (1/1024)^(j/31)
    float th = (float)t * fr;
    tab[idx * 2]     = cosf(th);
    tab[idx * 2 + 1] = sinf(th);
}

// ============ 256x256 8-phase bf16 GEMM (m201 template, plain HIP) ============
// C[16384][2048] = A[16384][2048] * Bt[n][k]^T.  BK=64 as two K-halves of 32.
// 512 thr = 8 waves (2M x 4N), per-wave 128x64 out = acc[8][4].
// LDS 128 KiB: op x buf x kh regions of 16 KB (256 rows x 64 B).
// Swizzle: 16B-chunk ^= (row>>1)&3  (involution; pre-swizzled global source,
// linear gld_lds dest, swizzled ds_read).
// Schedule/K-tile: ph1[kh0,mh0]+stgA(t+1,kh1) ph2[kh0,mh1]+stgB(t+1,kh1)
//                  ph3[kh1,mh0]+stgA(t+2,kh0) ph4[kh1,mh1]+stgB(t+2,kh0)+vmcnt(4)
// vmcnt(4) leaves tile t+2's kh0 (4 loads) in flight across the tile barrier.
#define AOFF(buf, kh) ((buf) * 32768 + (kh) * 16384)
#define BOFF(buf, kh) (65536 + (buf) * 32768 + (kh) * 16384)

#define STG_A(BUFX, KHX, KKX) do {                                                 \
    gld16(asrc0 + ((KKX) + (KHX) * 32) * 2, lds + AOFF(BUFX, KHX) + ldst);         \
    gld16(asrc1 + ((KKX) + (KHX) * 32) * 2, lds + AOFF(BUFX, KHX) + 8192 + ldst);  \
} while (0)
#define STG_B(BUFX, KHX, KKX) do {                                                 \
    gld16(bsrc0 + ((KKX) + (KHX) * 32) * 2, lds + BOFF(BUFX, KHX) + ldst);         \
    gld16(bsrc1 + ((KKX) + (KHX) * 32) * 2, lds + BOFF(BUFX, KHX) + 8192 + ldst);  \
} while (0)

#define PHASE(BUF, KH, MH, LDB, STAGE_STMT, TAILVM) do {                           \
    bf16x8 af_[4];                                                                 \
    const char* ab_ = lds + AOFF(BUF, KH);                                         \
    _Pragma("unroll")                                                              \
    for (int mi_ = 0; mi_ < 4; ++mi_)                                              \
        af_[mi_] = *(const bf16x8*)(ab_ + offA[(MH) * 4 + mi_]);                   \
    if (LDB) {                                                                     \
        const char* bb_ = lds + BOFF(BUF, KH);                                     \
        _Pragma("unroll")                                                          \
        for (int ni_ = 0; ni_ < 4; ++ni_)                                          \
            bfr[ni_] = *(const bf16x8*)(bb_ + offB[ni_]);                          \
    }                                                                              \
    STAGE_STMT;                                                                    \
    __builtin_amdgcn_s_barrier();                                                  \
    asm volatile("s_waitcnt lgkmcnt(0)" ::: "memory");                             \
    __builtin_amdgcn_sched_barrier(0);                                             \
    __builtin_amdgcn_s_setprio(1);                                                 \
    _Pragma("unroll")                                                              \
    for (int mi_ = 0; mi_ < 4; ++mi_)                                              \
        _Pragma("unroll")                                                          \
        for (int ni_ = 0; ni_ < 4; ++ni_)                                          \
            acc[(MH) * 4 + mi_][ni_] = __builtin_amdgcn_mfma_f32_16x16x32_bf16(    \
                af_[mi_], bfr[ni_], acc[(MH) * 4 + mi_][ni_], 0, 0, 0);            \
    __builtin_amdgcn_s_setprio(0);                                                 \
    TAILVM;                                                                        \
    __builtin_amdgcn_s_barrier();                                                  \
} while (0)

#define TILE(BUF, TC) do {                                                         \
    int tp1_ = (TC) + 1 < 32 ? (TC) + 1 : 31;                                      \
    int tp2_ = (TC) + 2 < 32 ? (TC) + 2 : 31;                                      \
    int kb1_ = tp1_ * 64, kb2_ = tp2_ * 64;                                        \
    PHASE(BUF, 0, 0, 1, STG_A((BUF) ^ 1, 1, kb1_), ((void)0));                     \
    PHASE(BUF, 0, 1, 0, STG_B((BUF) ^ 1, 1, kb1_), ((void)0));                     \
    PHASE(BUF, 1, 0, 1, STG_A(BUF, 0, kb2_), ((void)0));                           \
    PHASE(BUF, 1, 1, 0, STG_B(BUF, 0, kb2_),                                       \
          asm volatile("s_waitcnt vmcnt(4)" ::: "memory"));                        \
} while (0)

template <int OUTF32>
__global__ __launch_bounds__(512, 2) void k_gemm(const ushort* __restrict__ A, const ushort* __restrict__ Bt,
                                                 float* __restrict__ Cf, ushort* __restrict__ Cb) {
    __shared__ __align__(128) char lds[131072];
    const int tid = threadIdx.x;
    const int wid = tid >> 6, lane = tid & 63;
    const int wm = wid >> 2, wn = wid & 3;
    const int lrow = lane & 15, q = lane >> 4;

    // XCD-bijective swizzle: 512 wgs, 64/XCD mapped as 8m x 8n
    int bid = blockIdx.x;
    int xcd = bid & 7, local = bid >> 3;
    size_t m0 = (size_t)(xcd * 8 + (local >> 3)) * 256;
    size_t n0 = (size_t)(local & 7) * 256;

    // per-thread fragment ds_read byte offsets (swizzled)
    int offA[8], offB[4];
#pragma unroll
    for (int mi = 0; mi < 8; ++mi) {
        int R = wm * 128 + mi * 16 + lrow;
        offA[mi] = R * 64 + ((q ^ ((R >> 1) & 3)) << 4);
    }
#pragma unroll
    for (int ni = 0; ni < 4; ++ni) {
        int R = wn * 64 + ni * 16 + lrow;
        offB[ni] = R * 64 + ((q ^ ((R >> 1) & 3)) << 4);
    }

    // staging: per thread 2 gld16 per (op,kh) region; pre-swizzled global source
    int srow0 = tid >> 2;
    int cw = (tid & 3) ^ ((tid >> 3) & 3);
    const char* asrc0 = (const char*)(A + (m0 + srow0) * 2048 + cw * 8);
    const char* asrc1 = (const char*)(A + (m0 + srow0 + 128) * 2048 + cw * 8);
    const char* bsrc0 = (const char*)(Bt + (n0 + srow0) * 2048 + cw * 8);
    const char* bsrc1 = (const char*)(Bt + (n0 + srow0 + 128) * 2048 + cw * 8);
    const int ldst = tid * 16;

    f32x4 acc[8][4] = {};
    bf16x8 bfr[4];

    // prologue: tile0 (kh0+kh1) + tile1 kh0 = 12 loads; vmcnt(4) leaves tile1-kh0 in flight
    STG_A(0, 0, 0); STG_B(0, 0, 0); STG_A(0, 1, 0); STG_B(0, 1, 0);
    STG_A(1, 0, 64); STG_B(1, 0, 64);
    asm volatile("s_waitcnt vmcnt(4)" ::: "memory");
    __builtin_amdgcn_s_barrier();

#pragma unroll 1
    for (int t = 0; t < 32; t += 2) {
        TILE(0, t);
        TILE(1, t + 1);
    }

#pragma unroll
    for (int mi = 0; mi < 8; ++mi)
#pragma unroll
        for (int ni = 0; ni < 4; ++ni)
#pragma unroll
            for (int i = 0; i < 4; ++i) {
                size_t row = m0 + wm * 128 + mi * 16 + (lane >> 4) * 4 + i;
                size_t col = n0 + wn * 64 + ni * 16 + lrow;
                if (OUTF32) Cf[row * 2048 + col] = acc[mi][ni][i];
                else        Cb[row * 2048 + col] = f2bu(acc[mi][ni][i]);
            }
}

// ---------------- rope + reshape ----------------
// mode 0: q -> natural [bh][t][d] (roped)
// mode 1: k -> natural [bh][t][d] (roped) + kT [bh][d][t] (roped, * k_decay[s])
// mode 2: v -> vT [bh][e][t]
__global__ __launch_bounds__(256) void k_reshape(const ushort* __restrict__ Cin, ushort* __restrict__ outN,
                                                 ushort* __restrict__ outT, const float* __restrict__ rt, int mode) {
    int blk = blockIdx.x;           // (bh)*32 + c
    int c = blk & 31, bh = blk >> 5, b = bh >> 4, h = bh & 15;
    __shared__ __align__(16) ushort lt[128][136];
    int tid = threadIdx.x;
    int d = tid & 63, rq = tid >> 6;
    float slope = exp2f(-0.5f * (float)(h + 1));
    float l2r = -slope * LOG2E;
    for (int rp = 0; rp < 32; ++rp) {
        int tr = rp * 4 + rq;
        int t = c * 128 + tr;
        const ushort* src = Cin + ((size_t)(b * 4096 + t)) * 2048 + h * 128;
        float x1 = bu2f(src[d]), x2 = bu2f(src[d + 64]);
        float y1 = x1, y2 = x2;
        if (mode != 2 && d < 32) {
            float cs = rt[(t * 32 + d) * 2], sn = rt[(t * 32 + d) * 2 + 1];
            y1 = x1 * cs + x2 * sn;
            y2 = x2 * cs - x1 * sn;
        }
        if (mode != 2) {
            ushort* dstN = outN + ((size_t)bh * 4096 + t) * 128;
            dstN[d] = f2bu(y1); dstN[d + 64] = f2bu(y2);
        }
        if (mode != 0) { lt[tr][d] = f2bu(y1); lt[tr][d + 64] = f2bu(y2); }
    }
    if (mode == 0) return;
    __syncthreads();
    int dd = tid >> 1, half = tid & 1;
    ushort* dstT = outT + ((size_t)bh * 128 + dd) * 4096 + c * 128 + half * 64;
    for (int j8 = 0; j8 < 8; ++j8) {
        u16x8 tmp;
#pragma unroll
        for (int j = 0; j < 8; ++j) {
            int s = half * 64 + j8 * 8 + j;
            float v = bu2f(lt[s][dd]);
            if (mode == 1) v *= exp2f(l2r * (float)(127 - s));
            tmp[j] = f2bu(v);
        }
        *(u16x8*)(dstT + j8 * 8) = tmp;
    }
}

// ---------------- pass1: chunk-local KVt[e][d] = sum_s v[s][e]*kd[s]*k[s][d] ----------------
__global__ __launch_bounds__(256) void k_pass1(const ushort* __restrict__ kTa, const ushort* __restrict__ vTa,
                                               float* __restrict__ KVc) {
    int blk = blockIdx.x;           // bh*32 + c
    int c = blk & 31, bh = blk >> 5;
    __shared__ __align__(16) ushort lv[128][136];
    __shared__ __align__(16) ushort lk[128][136];
    int tid = threadIdx.x;
#pragma unroll
    for (int i = 0; i < 8; ++i) {
        int idx = i * 256 + tid; int row = idx >> 4, cb = (idx & 15) * 8;
        *(bf16x8*)&lv[row][cb] = *(const bf16x8*)(vTa + ((size_t)bh * 128 + row) * 4096 + c * 128 + cb);
        *(bf16x8*)&lk[row][cb] = *(const bf16x8*)(kTa + ((size_t)bh * 128 + row) * 4096 + c * 128 + cb);
    }
    __syncthreads();
    int wid = tid >> 6, lane = tid & 63, wr = wid >> 1, wc = wid & 1;
    int lrow = lane & 15, lko = (lane >> 4) * 8;
    f32x4 acc[4][4] = {};
#pragma unroll
    for (int ks = 0; ks < 4; ++ks) {
        bf16x8 a[4], bb[4];
#pragma unroll
        for (int mi = 0; mi < 4; ++mi) a[mi] = *(const bf16x8*)&lv[wr * 64 + mi * 16 + lrow][ks * 32 + lko];
#pragma unroll
        for (int ni = 0; ni < 4; ++ni) bb[ni] = *(const bf16x8*)&lk[wc * 64 + ni * 16 + lrow][ks * 32 + lko];
#pragma unroll
        for (int mi = 0; mi < 4; ++mi)
#pragma unroll
            for (int ni = 0; ni < 4; ++ni)
                acc[mi][ni] = __builtin_amdgcn_mfma_f32_16x16x32_bf16(a[mi], bb[ni], acc[mi][ni], 0, 0, 0);
    }
    float* out = KVc + (size_t)blk * 16384;
#pragma unroll
    for (int mi = 0; mi < 4; ++mi)
#pragma unroll
        for (int ni = 0; ni < 4; ++ni)
#pragma unroll
            for (int i = 0; i < 4; ++i)
                out[(wr * 64 + mi * 16 + (lane >> 4) * 4 + i) * 128 + wc * 64 + ni * 16 + lrow] = acc[mi][ni][i];
}

// ---------------- pass2: prefix scan over chunks (fp32 state), emit bf16 prefixes ----------------
__global__ __launch_bounds__(256) void k_scan(const float* __restrict__ KVc, ushort* __restrict__ KVbf) {
    int bh = blockIdx.x >> 4, seg = blockIdx.x & 15, h = bh & 15;
    float slope = exp2f(-0.5f * (float)(h + 1));
    float rC = exp2f(-slope * LOG2E * 128.0f);
    int off = seg * 1024 + threadIdx.x * 4;
    f32x4 st = {0.f, 0.f, 0.f, 0.f};
    for (int c = 0; c < 32; ++c) {
        size_t base = ((size_t)bh * 32 + c) * 16384 + off;
        f32x4 v = *(const f32x4*)(KVc + base);
        u16x4 o = { f2bu(st.x), f2bu(st.y), f2bu(st.z), f2bu(st.w) };
        *(u16x4*)(KVbf + base) = o;
        st = st * rC + v;
    }
}

// ---------------- pass3: out = diag(q_decay)*(q@KV) + (dmask o (q@k^T))@v ----------------
__global__ __launch_bounds__(512) void k_pass3(const ushort* __restrict__ qa, const ushort* __restrict__ ka,
                                               const ushort* __restrict__ vTa, const ushort* __restrict__ KVbf,
                                               ushort* __restrict__ attn) {
    int blk = blockIdx.x;           // bh*32 + c
    int c = blk & 31, bh = blk >> 5, h = bh & 15;
    __shared__ __align__(16) ushort lq[128][136];
    __shared__ __align__(16) ushort lk[128][136];   // later reused as P
    __shared__ __align__(16) ushort lv[128][136];
    int tid = threadIdx.x;
#pragma unroll
    for (int i = 0; i < 4; ++i) {
        int idx = i * 512 + tid; int row = idx >> 4, cb = (idx & 15) * 8;
        *(bf16x8*)&lq[row][cb] = *(const bf16x8*)(qa + ((size_t)bh * 4096 + c * 128 + row) * 128 + cb);
        *(bf16x8*)&lk[row][cb] = *(const bf16x8*)(ka + ((size_t)bh * 4096 + c * 128 + row) * 128 + cb);
        *(bf16x8*)&lv[row][cb] = *(const bf16x8*)(vTa + ((size_t)bh * 128 + row) * 4096 + c * 128 + cb);
    }
    __syncthreads();
    int wid = tid >> 6, lane = tid & 63;
    int wr = wid >> 2, wc = wid & 3;          // 2 x 4 wave grid: 64 t-rows x 32 cols
    int lrow = lane & 15, lko = (lane >> 4) * 8;
    float slope = exp2f(-0.5f * (float)(h + 1));
    float l2r = -slope * LOG2E;

    // scores = q @ k^T (quadrant t: wr*64.., s: wc*32..)
    f32x4 accs[4][2] = {};
#pragma unroll
    for (int kd = 0; kd < 4; ++kd) {
        bf16x8 a[4], bb[2];
#pragma unroll
        for (int mi = 0; mi < 4; ++mi) a[mi] = *(const bf16x8*)&lq[wr * 64 + mi * 16 + lrow][kd * 32 + lko];
#pragma unroll
        for (int ni = 0; ni < 2; ++ni) bb[ni] = *(const bf16x8*)&lk[wc * 32 + ni * 16 + lrow][kd * 32 + lko];
#pragma unroll
        for (int mi = 0; mi < 4; ++mi)
#pragma unroll
            for (int ni = 0; ni < 2; ++ni)
                accs[mi][ni] = __builtin_amdgcn_mfma_f32_16x16x32_bf16(a[mi], bb[ni], accs[mi][ni], 0, 0, 0);
    }
    __syncthreads();   // everyone done reading lk; it becomes the P buffer

    // inter = q @ KV (B-frags straight from global bf16 KV prefix)
    f32x4 acc[4][2] = {};
#pragma unroll
    for (int kd = 0; kd < 4; ++kd) {
        bf16x8 a[4], bb[2];
#pragma unroll
        for (int mi = 0; mi < 4; ++mi) a[mi] = *(const bf16x8*)&lq[wr * 64 + mi * 16 + lrow][kd * 32 + lko];
#pragma unroll
        for (int ni = 0; ni < 2; ++ni)
            bb[ni] = *(const bf16x8*)(KVbf + (size_t)blk * 16384 + (size_t)(wc * 32 + ni * 16 + lrow) * 128 + kd * 32 + lko);
#pragma unroll
        for (int mi = 0; mi < 4; ++mi)
#pragma unroll
            for (int ni = 0; ni < 2; ++ni)
                acc[mi][ni] = __builtin_amdgcn_mfma_f32_16x16x32_bf16(a[mi], bb[ni], acc[mi][ni], 0, 0, 0);
    }

    // P = dmask o scores  -> write bf16 into lk
#pragma unroll
    for (int mi = 0; mi < 4; ++mi)
#pragma unroll
        for (int ni = 0; ni < 2; ++ni)
#pragma unroll
            for (int i = 0; i < 4; ++i) {
                int t = wr * 64 + mi * 16 + (lane >> 4) * 4 + i;
                int s = wc * 32 + ni * 16 + lrow;
                int dt = t - s;
                float w = (dt < 0) ? 0.f : exp2f(l2r * (float)dt);
                lk[t][s] = f2bu(accs[mi][ni][i] * w);
            }

    // scale inter by q_decay[t] = r^(t+1)
#pragma unroll
    for (int mi = 0; mi < 4; ++mi)
#pragma unroll
        for (int ni = 0; ni < 2; ++ni)
#pragma unroll
            for (int i = 0; i < 4; ++i) {
                int t = wr * 64 + mi * 16 + (lane >> 4) * 4 + i;
                acc[mi][ni][i] *= exp2f(l2r * (float)(t + 1));
            }
    __syncthreads();

    // intra: P @ v (A = P from lk, B from vT)
#pragma unroll
    for (int ks = 0; ks < 4; ++ks) {
        bf16x8 a[4], bb[2];
#pragma unroll
        for (int mi = 0; mi < 4; ++mi) a[mi] = *(const bf16x8*)&lk[wr * 64 + mi * 16 + lrow][ks * 32 + lko];
#pragma unroll
        for (int ni = 0; ni < 2; ++ni) bb[ni] = *(const bf16x8*)&lv[wc * 32 + ni * 16 + lrow][ks * 32 + lko];
#pragma unroll
        for (int mi = 0; mi < 4; ++mi)
#pragma unroll
            for (int ni = 0; ni < 2; ++ni)
                acc[mi][ni] = __builtin_amdgcn_mfma_f32_16x16x32_bf16(a[mi], bb[ni], acc[mi][ni], 0, 0, 0);
    }

    ushort* out = attn + ((size_t)bh * 4096 + c * 128) * 128;
#pragma unroll
    for (int mi = 0; mi < 4; ++mi)
#pragma unroll
        for (int ni = 0; ni < 2; ++ni)
#pragma unroll
            for (int i = 0; i < 4; ++i)
                out[(size_t)(wr * 64 + mi * 16 + (lane >> 4) * 4 + i) * 128 + wc * 32 + ni * 16 + lrow] =
                    f2bu(acc[mi][ni][i]);
}

// ---------------- RMS norm + [b,h,t,d] -> [token][e] ----------------
__global__ __launch_bounds__(256) void k_rms(const ushort* __restrict__ attn, const float* __restrict__ w,
                                             ushort* __restrict__ normed) {
    int tok = blockIdx.x; int b = tok >> 12, t = tok & 4095;
    int tid = threadIdx.x;
    int e0 = tid * 8; int h = e0 >> 7, d0 = e0 & 127;
    bf16x8 v = *(const bf16x8*)(attn + (((size_t)(b * 16 + h) * 4096 + t) * 128 + d0));
    float f[8]; float ss = 0.f;
#pragma unroll
    for (int j = 0; j < 8; ++j) { f[j] = (float)v[j]; ss += f[j] * f[j]; }
#pragma unroll
    for (int o = 1; o < 64; o <<= 1) ss += __shfl_xor(ss, o, 64);
    __shared__ float red[4];
    if ((tid & 63) == 0) red[tid >> 6] = ss;
    __syncthreads();
    float tot = red[0] + red[1] + red[2] + red[3];
    float sc = rsqrtf(tot * (1.0f / 2048.0f) + 1e-5f);
    u16x8 ov;
#pragma unroll
    for (int j = 0; j < 8; ++j) ov[j] = f2bu(f[j] * sc * w[e0 + j]);
    *(u16x8*)(normed + (size_t)tok * 2048 + e0) = ov;
}

// ---------------- launch ----------------
// ws layout (MiB): 0 WtQ, 8 WtK, 16 WtV, 24 WtO, 32 xb(64), 96 Cbuf(64),
// 160 qa(64), 224 ka(64), 288 kTa(64), 352 vTa(64), 416 ropetab(1).
// Reuse after liveness ends: KVc f32 @32 (128), KVbf @288 (64), attn @32 (64), normed @96 (64).
// Requires ws_size >= 417 MiB.
extern "C" void kernel_launch(void* const* d_in, const int* in_sizes, int n_in,
                              void* d_out, int out_size, void* d_ws, size_t ws_size,
                              hipStream_t stream) {
    const float* x    = (const float*)d_in[0];
    const float* Wq   = (const float*)d_in[1];
    const float* Wk   = (const float*)d_in[2];
    const float* Wv   = (const float*)d_in[3];
    const float* Wo   = (const float*)d_in[4];
    const float* rmsw = (const float*)d_in[5];
    char* ws = (char*)d_ws;
    const size_t MiB = 1ull << 20;
    ushort* WtQ  = (ushort*)(ws + 0);
    ushort* WtK  = (ushort*)(ws + 8 * MiB);
    ushort* WtV  = (ushort*)(ws + 16 * MiB);
    ushort* WtO  = (ushort*)(ws + 24 * MiB);
    ushort* xb   = (ushort*)(ws + 32 * MiB);
    ushort* Cbuf = (ushort*)(ws + 96 * MiB);
    ushort* qa   = (ushort*)(ws + 160 * MiB);
    ushort* ka   = (ushort*)(ws + 224 * MiB);
    ushort* kTa  = (ushort*)(ws + 288 * MiB);
    ushort* vTa  = (ushort*)(ws + 352 * MiB);
    float*  rt   = (float*)(ws + 416 * MiB);
    float*  KVc  = (float*)(ws + 32 * MiB);
    ushort* KVbf = (ushort*)(ws + 288 * MiB);
    ushort* attn = (ushort*)(ws + 32 * MiB);
    ushort* nrm  = (ushort*)(ws + 96 * MiB);

    k_cvt<<<32768, 256, 0, stream>>>(x, xb, 8388608);
    dim3 gw(64, 64);
    k_twt<<<gw, 256, 0, stream>>>(Wq, WtQ);
    k_twt<<<gw, 256, 0, stream>>>(Wk, WtK);
    k_twt<<<gw, 256, 0, stream>>>(Wv, WtV);
    k_twt<<<gw, 256, 0, stream>>>(Wo, WtO);
    k_rope<<<512, 256, 0, stream>>>(rt);

    k_gemm<0><<<512, 512, 0, stream>>>(xb, WtQ, nullptr, Cbuf);
    k_reshape<<<2048, 256, 0, stream>>>(Cbuf, qa, nullptr, rt, 0);
    k_gemm<0><<<512, 512, 0, stream>>>(xb, WtK, nullptr, Cbuf);
    k_reshape<<<2048, 256, 0, stream>>>(Cbuf, ka, kTa, rt, 1);
    k_gemm<0><<<512, 512, 0, stream>>>(xb, WtV, nullptr, Cbuf);
    k_reshape<<<2048, 256, 0, stream>>>(Cbuf, nullptr, vTa, rt, 2);

    k_pass1<<<2048, 256, 0, stream>>>(kTa, vTa, KVc);
    k_scan<<<1024, 256, 0, stream>>>(KVc, KVbf);
    k_pass3<<<2048, 512, 0, stream>>>(qa, ka, vTa, KVbf, attn);

    k_rms<<<16384, 256, 0, stream>>>(attn, rmsw, nrm);
    k_gemm<1><<<512, 512, 0, stream>>>(nrm, WtO, (float*)d_out, nullptr);
}